// Round 3
// baseline (570.169 us; speedup 1.0000x reference)
//
#include <hip/hip_runtime.h>

#define BB 2
#define SS 2048
#define DD 1024
#define HH 16
#define DKK 64
#define MROWS (BB*SS)
#define NEG_BIG (-30000.0f)

typedef unsigned short u16;
typedef unsigned int u32;
typedef __bf16 bf16x8 __attribute__((ext_vector_type(8)));
typedef float f32x4 __attribute__((ext_vector_type(4)));

__device__ __forceinline__ float bf2f(u16 u) {
    union { u32 i; float f; } w;
    w.i = ((u32)u) << 16;
    return w.f;
}
__device__ __forceinline__ u16 f2bf(float f) {
    union { float f; u32 i; } w;
    w.f = f;
    u32 u = w.i;
    return (u16)((u + 0x7fffu + ((u >> 16) & 1u)) >> 16);
}
// pack two f32 -> two bf16 (truncation; compiler emits v_perm)
__device__ __forceinline__ u32 pack2(float lo, float hi) {
    union { float f; u32 i; } a, b;
    a.f = lo; b.f = hi;
    return (a.i >> 16) | (b.i & 0xffff0000u);
}

// ---------------------------------------------------------------------------
// NT GEMM: out[m,n] = sum_k A[m,k]*W[n,k] + bias[n]  (out is bf16)
// A: float32 (ABF16=0) or bf16 (ABF16=1). W/bias: float32.
// M=4096, N=1024, K=1024. mode 0: head layout [B*H,S,DK]; mode 1: [m,n].
// 128x128 tile, 4 waves (2x2), each wave 4x4 MFMA 16x16x32 tiles, BK=64.
// ---------------------------------------------------------------------------
template<int ABF16>
__global__ __launch_bounds__(256, 2)
void gemm_nt(const void* __restrict__ Av, const float* __restrict__ W,
             const float* __restrict__ bias, u16* __restrict__ out, int mode)
{
    __shared__ __align__(16) u16 As[128 * 64];
    __shared__ __align__(16) u16 Bs[128 * 64];
    const int K = 1024;
    int tid  = threadIdx.x;
    int wave = tid >> 6;
    int lane = tid & 63;
    int quad = lane >> 4;
    int l16  = lane & 15;
    int bm = blockIdx.x >> 3;   // 32 M-tiles
    int bn = blockIdx.x & 7;    // 8 N-tiles
    int row0 = bm * 128, col0 = bn * 128;
    int wm = (wave >> 1) * 64;
    int wn = (wave & 1) * 64;

    f32x4 acc[4][4] = {};

    int srow = tid >> 3;        // 0..31
    int scol = (tid & 7) * 8;   // 0..56 (element index)

    const u16*  Ab = (const u16*)Av;
    const float* Af = (const float*)Av;

    for (int k0 = 0; k0 < K; k0 += 64) {
        uint4 aval[4], bval[4];
        #pragma unroll
        for (int c = 0; c < 4; ++c) {
            int r = srow + c * 32;
            if (ABF16) {
                aval[c] = *(const uint4*)(Ab + (size_t)(row0 + r) * K + k0 + scol);
            } else {
                const float* ap = Af + (size_t)(row0 + r) * K + k0 + scol;
                float4 lo = *(const float4*)ap;
                float4 hi = *(const float4*)(ap + 4);
                aval[c].x = pack2(lo.x, lo.y);
                aval[c].y = pack2(lo.z, lo.w);
                aval[c].z = pack2(hi.x, hi.y);
                aval[c].w = pack2(hi.z, hi.w);
            }
            const float* bp = W + (size_t)(col0 + r) * K + k0 + scol;
            float4 blo = *(const float4*)bp;
            float4 bhi = *(const float4*)(bp + 4);
            bval[c].x = pack2(blo.x, blo.y);
            bval[c].y = pack2(blo.z, blo.w);
            bval[c].z = pack2(bhi.x, bhi.y);
            bval[c].w = pack2(bhi.z, bhi.w);
        }
        __syncthreads();
        #pragma unroll
        for (int c = 0; c < 4; ++c) {
            int r = srow + c * 32;
            *(uint4*)&As[r * 64 + scol] = aval[c];
            *(uint4*)&Bs[r * 64 + scol] = bval[c];
        }
        __syncthreads();
        #pragma unroll
        for (int kk = 0; kk < 2; ++kk) {
            bf16x8 af[4], bfv[4];
            #pragma unroll
            for (int i = 0; i < 4; ++i)
                af[i] = *(const bf16x8*)&As[(wm + i * 16 + l16) * 64 + kk * 32 + quad * 8];
            #pragma unroll
            for (int j = 0; j < 4; ++j)
                bfv[j] = *(const bf16x8*)&Bs[(wn + j * 16 + l16) * 64 + kk * 32 + quad * 8];
            #pragma unroll
            for (int i = 0; i < 4; ++i)
                #pragma unroll
                for (int j = 0; j < 4; ++j)
                    acc[i][j] = __builtin_amdgcn_mfma_f32_16x16x32_bf16(af[i], bfv[j], acc[i][j], 0, 0, 0);
        }
    }

    // epilogue: C row = wm+i*16+quad*4+r, col = wn+j*16+l16
    #pragma unroll
    for (int j = 0; j < 4; ++j) {
        int n = col0 + wn + j * 16 + l16;
        float bvv = bias[n];
        #pragma unroll
        for (int i = 0; i < 4; ++i) {
            int rbase = row0 + wm + i * 16 + quad * 4;
            #pragma unroll
            for (int r = 0; r < 4; ++r) {
                int m = rbase + r;
                float v = acc[i][j][r] + bvv;
                if (mode == 0) {
                    int b = m >> 11, s = m & (SS - 1);
                    int h = n >> 6, dk = n & 63;
                    out[(((size_t)(b * HH + h)) * SS + s) * DKK + dk] = f2bf(v);
                } else {
                    out[(size_t)m * DD + n] = f2bf(v);
                }
            }
        }
    }
}

// ---------------------------------------------------------------------------
// Flash attention, causal, additive per-key penalty -cpen*complexity[b,k].
// Q/K/V in bf16 head layout [B*H, S, DK]. 4 waves; wave owns 16 q rows;
// block covers 64 q rows; iterates 64-key tiles kt=0..qt. ctx out bf16.
// ---------------------------------------------------------------------------
__global__ __launch_bounds__(256, 2)
void attn_kernel(const u16* __restrict__ Qh, const u16* __restrict__ Kh,
                 const u16* __restrict__ Vh, const float* __restrict__ comp,
                 const float* __restrict__ cpen_p, u16* __restrict__ ctx)
{
    __shared__ __align__(16) u16 Kl[64 * 64];
    __shared__ __align__(16) u16 Vt[64 * 64];        // [d][k]
    __shared__ __align__(16) u16 Pl[4][16 * 64];     // per-wave [qrow][k]

    int tid  = threadIdx.x;
    int wave = tid >> 6, lane = tid & 63;
    int quad = lane >> 4, l16 = lane & 15;
    int qt = blockIdx.x & 31;       // 32 q-tiles of 64
    int bh = blockIdx.x >> 5;       // 0..31
    int b = bh >> 4;
    int h = bh & 15;
    float cpen = cpen_p[0];

    const u16* Qb = Qh + (size_t)bh * SS * DKK;
    const u16* Kb = Kh + (size_t)bh * SS * DKK;
    const u16* Vb = Vh + (size_t)bh * SS * DKK;

    int q0 = qt * 64;
    int qrow = q0 + wave * 16 + l16;
    bf16x8 qf0 = *(const bf16x8*)&Qb[(size_t)qrow * DKK + quad * 8];
    bf16x8 qf1 = *(const bf16x8*)&Qb[(size_t)qrow * DKK + 32 + quad * 8];

    f32x4 o[4] = {};
    float mrow[4] = {NEG_BIG, NEG_BIG, NEG_BIG, NEG_BIG};
    float lrow[4] = {0.f, 0.f, 0.f, 0.f};
    int myq = q0 + wave * 16 + quad * 4;

    int srow = tid >> 2;          // 0..63
    int scol = (tid & 3) * 16;    // 0,16,32,48

    for (int kt = 0; kt <= qt; ++kt) {
        // prefetch K tile + V tile slices to registers
        const u16* ks = Kb + (size_t)(kt * 64 + srow) * DKK + scol;
        uint4 k0v = *(const uint4*)ks;
        uint4 k1v = *(const uint4*)(ks + 8);
        int vrow = tid & 63;
        int vd0  = (tid >> 6) * 16;
        const u16* vs = Vb + (size_t)(kt * 64 + vrow) * DKK + vd0;
        __align__(16) u16 tmp[16];
        *(uint4*)&tmp[0] = *(const uint4*)vs;
        *(uint4*)&tmp[8] = *(const uint4*)(vs + 8);

        __syncthreads();
        *(uint4*)&Kl[srow * 64 + scol]     = k0v;
        *(uint4*)&Kl[srow * 64 + scol + 8] = k1v;
        #pragma unroll
        for (int t = 0; t < 16; ++t) Vt[(vd0 + t) * 64 + vrow] = tmp[t];
        __syncthreads();

        // scores: S = Q K^T
        f32x4 sc[4] = {};
        #pragma unroll
        for (int jj = 0; jj < 4; ++jj) {
            bf16x8 kf0 = *(const bf16x8*)&Kl[(jj * 16 + l16) * 64 + quad * 8];
            bf16x8 kf1 = *(const bf16x8*)&Kl[(jj * 16 + l16) * 64 + 32 + quad * 8];
            sc[jj] = __builtin_amdgcn_mfma_f32_16x16x32_bf16(qf0, kf0, sc[jj], 0, 0, 0);
            sc[jj] = __builtin_amdgcn_mfma_f32_16x16x32_bf16(qf1, kf1, sc[jj], 0, 0, 0);
        }

        bool diag = (kt == qt);
        #pragma unroll
        for (int jj = 0; jj < 4; ++jj) {
            int kcol = kt * 64 + jj * 16 + l16;
            float pen = cpen * comp[b * SS + kcol];
            #pragma unroll
            for (int r = 0; r < 4; ++r) {
                float sv = sc[jj][r] * 0.125f - pen;
                if (diag && (kcol > myq + r)) sv = NEG_BIG;
                sc[jj][r] = sv;
            }
        }

        // online softmax (row spans the 16 lanes of this quad-group)
        float mnew[4], alpha[4];
        #pragma unroll
        for (int r = 0; r < 4; ++r) {
            float mx = fmaxf(fmaxf(sc[0][r], sc[1][r]), fmaxf(sc[2][r], sc[3][r]));
            #pragma unroll
            for (int off = 1; off < 16; off <<= 1)
                mx = fmaxf(mx, __shfl_xor(mx, off, 64));
            mnew[r] = fmaxf(mrow[r], mx);
            alpha[r] = __expf(mrow[r] - mnew[r]);
            mrow[r] = mnew[r];
        }
        float lsum[4] = {0.f, 0.f, 0.f, 0.f};
        #pragma unroll
        for (int jj = 0; jj < 4; ++jj)
            #pragma unroll
            for (int r = 0; r < 4; ++r) {
                float p = __expf(sc[jj][r] - mnew[r]);
                sc[jj][r] = p;
                lsum[r] += p;
            }
        #pragma unroll
        for (int r = 0; r < 4; ++r) {
            float t = lsum[r];
            #pragma unroll
            for (int off = 1; off < 16; off <<= 1)
                t += __shfl_xor(t, off, 64);
            lrow[r] = lrow[r] * alpha[r] + t;
        }
        #pragma unroll
        for (int jj = 0; jj < 4; ++jj)
            #pragma unroll
            for (int r = 0; r < 4; ++r)
                o[jj][r] *= alpha[r];

        // P: C-layout -> LDS -> A-layout (per-wave buffer, same-wave in-order DS)
        #pragma unroll
        for (int jj = 0; jj < 4; ++jj)
            #pragma unroll
            for (int r = 0; r < 4; ++r)
                Pl[wave][(quad * 4 + r) * 64 + jj * 16 + l16] = f2bf(sc[jj][r]);

        #pragma unroll
        for (int kk = 0; kk < 2; ++kk) {
            bf16x8 pf = *(const bf16x8*)&Pl[wave][l16 * 64 + kk * 32 + quad * 8];
            #pragma unroll
            for (int jj = 0; jj < 4; ++jj) {
                bf16x8 vf = *(const bf16x8*)&Vt[(jj * 16 + l16) * 64 + kk * 32 + quad * 8];
                o[jj] = __builtin_amdgcn_mfma_f32_16x16x32_bf16(pf, vf, o[jj], 0, 0, 0);
            }
        }
    }

    #pragma unroll
    for (int r = 0; r < 4; ++r) lrow[r] = 1.f / lrow[r];
    #pragma unroll
    for (int jj = 0; jj < 4; ++jj)
        #pragma unroll
        for (int r = 0; r < 4; ++r) {
            int q = q0 + wave * 16 + quad * 4 + r;
            int d = jj * 16 + l16;
            ctx[((size_t)(b * SS + q)) * DD + h * DKK + d] = f2bf(o[jj][r] * lrow[r]);
        }
}

// ---------------------------------------------------------------------------
// Residual + LayerNorm: out = LN(po + query) * g + b. One block per row.
// po: bf16, query/g/b/out: float32.
// ---------------------------------------------------------------------------
__global__ __launch_bounds__(256)
void ln_res(const u16* __restrict__ po, const float* __restrict__ query,
            const float* __restrict__ g, const float* __restrict__ bb,
            float* __restrict__ out)
{
    int row = blockIdx.x;
    int tid = threadIdx.x;
    int lane = tid & 63, wave = tid >> 6;
    size_t base = (size_t)row * DD + tid * 4;
    __align__(8) u16 tp[4];
    *(uint2*)tp = *(const uint2*)(po + base);
    float4 q4 = *(const float4*)(query + base);
    float x[4];
    x[0] = bf2f(tp[0]) + q4.x;
    x[1] = bf2f(tp[1]) + q4.y;
    x[2] = bf2f(tp[2]) + q4.z;
    x[3] = bf2f(tp[3]) + q4.w;
    float s1 = 0.f, s2 = 0.f;
    #pragma unroll
    for (int i = 0; i < 4; ++i) { s1 += x[i]; s2 += x[i] * x[i]; }
    #pragma unroll
    for (int off = 1; off < 64; off <<= 1) {
        s1 += __shfl_xor(s1, off, 64);
        s2 += __shfl_xor(s2, off, 64);
    }
    __shared__ float red1[4], red2[4];
    if (lane == 0) { red1[wave] = s1; red2[wave] = s2; }
    __syncthreads();
    float t1 = red1[0] + red1[1] + red1[2] + red1[3];
    float t2 = red2[0] + red2[1] + red2[2] + red2[3];
    float mean = t1 * (1.f / 1024.f);
    float var  = fmaxf(t2 * (1.f / 1024.f) - mean * mean, 0.f);
    float rstd = rsqrtf(var + 1e-5f);
    float4 g4 = *(const float4*)(g + tid * 4);
    float4 b4 = *(const float4*)(bb + tid * 4);
    float4 ov;
    ov.x = (x[0] - mean) * rstd * g4.x + b4.x;
    ov.y = (x[1] - mean) * rstd * g4.y + b4.y;
    ov.z = (x[2] - mean) * rstd * g4.z + b4.z;
    ov.w = (x[3] - mean) * rstd * g4.w + b4.w;
    *(float4*)(out + base) = ov;
}

extern "C" void kernel_launch(void* const* d_in, const int* in_sizes, int n_in,
                              void* d_out, int out_size, void* d_ws, size_t ws_size,
                              hipStream_t stream)
{
    const float* query = (const float*)d_in[0];
    const float* key   = (const float*)d_in[1];
    const float* value = (const float*)d_in[2];
    const float* comp  = (const float*)d_in[3];
    // d_in[4] = mask (causal tril) — computed analytically, ignored
    const float* wq = (const float*)d_in[5];
    const float* bq = (const float*)d_in[6];
    const float* wk = (const float*)d_in[7];
    const float* bk = (const float*)d_in[8];
    const float* wv = (const float*)d_in[9];
    const float* bv = (const float*)d_in[10];
    const float* wo = (const float*)d_in[11];
    const float* bo = (const float*)d_in[12];
    const float* lng = (const float*)d_in[13];
    const float* lnb = (const float*)d_in[14];
    const float* cpen = (const float*)d_in[15];
    float* outp = (float*)d_out;

    const size_t NE = (size_t)MROWS * DD;   // 4 Mi elements
    // ws (bf16): qh, kh, vh = 24 MB. ctx lives in d_out's first 8 MB (dead
    // before ln_res overwrites d_out); O-proj bf16 output reuses qh (dead).
    u16* qh = (u16*)d_ws;
    u16* kh = qh + NE;
    u16* vh = kh + NE;
    u16* cx = (u16*)d_out;
    u16* po = qh;

    gemm_nt<0><<<256, 256, 0, stream>>>((const void*)query, wq, bq, qh, 0);
    gemm_nt<0><<<256, 256, 0, stream>>>((const void*)key,   wk, bk, kh, 0);
    gemm_nt<0><<<256, 256, 0, stream>>>((const void*)value, wv, bv, vh, 0);
    attn_kernel<<<1024, 256, 0, stream>>>(qh, kh, vh, comp, cpen, cx);
    gemm_nt<1><<<256, 256, 0, stream>>>((const void*)cx, wo, bo, po, 1);
    ln_res<<<MROWS, 256, 0, stream>>>(po, query, lng, lnb, outp);
}

// Round 4
// 451.206 us; speedup vs baseline: 1.2637x; 1.2637x over previous
//
#include <hip/hip_runtime.h>

#define BB 2
#define SS 2048
#define DD 1024
#define HH 16
#define DKK 64
#define MROWS (BB*SS)
#define NEG_BIG (-30000.0f)

typedef unsigned short u16;
typedef unsigned int u32;
typedef __bf16 bf16x8 __attribute__((ext_vector_type(8)));
typedef float f32x4 __attribute__((ext_vector_type(4)));

__device__ __forceinline__ float bf2f(u16 u) {
    union { u32 i; float f; } w; w.i = ((u32)u) << 16; return w.f;
}
__device__ __forceinline__ u16 f2bf(float f) {
    union { float f; u32 i; } w; w.f = f;
    u32 u = w.i;
    return (u16)((u + 0x7fffu + ((u >> 16) & 1u)) >> 16);
}
__device__ __forceinline__ u32 pack2(float lo, float hi) {
    union { float f; u32 i; } a, b; a.f = lo; b.f = hi;
    return (a.i >> 16) | (b.i & 0xffff0000u);
}
__device__ __forceinline__ void gl2lds16(const u16* g, u16* l) {
    __builtin_amdgcn_global_load_lds(
        (const __attribute__((address_space(1))) void*)g,
        (__attribute__((address_space(3))) void*)l, 16, 0, 0);
}

// ---------------------------------------------------------------------------
// f32 -> bf16 convert for the 4 weight matrices (1M elems each).
// ---------------------------------------------------------------------------
__global__ __launch_bounds__(256)
void cvt_w(const float* __restrict__ w0, const float* __restrict__ w1,
           const float* __restrict__ w2, const float* __restrict__ w3,
           u16* __restrict__ dst)
{
    const float* srcs[4] = {w0, w1, w2, w3};
    int seg = blockIdx.y;
    const float* s = srcs[seg];
    int i = (blockIdx.x * 256 + threadIdx.x) * 4;
    float4 v = *(const float4*)(s + i);
    u32 p0 = pack2(v.x, v.y), p1 = pack2(v.z, v.w);
    u32* d = (u32*)(dst + (size_t)seg * DD * DD + i);
    d[0] = p0; d[1] = p1;
}

// ---------------------------------------------------------------------------
// NT GEMM: out[m,n] = sum_k A[m,k]*W[n,k] + bias[n].  W: bf16. A: f32 or bf16.
// M=4096, N=1024, K=1024. Tiles: 128(M) x 64(N), BK=64, 4 waves (2x2),
// wave tile 64x32 = 4x2 MFMA 16x16x32 frags. Grid 512 (2 blocks/CU).
// MODE 0: head layout [B*H,S,DK]; MODE 1: plain [m,n]; MODE 2: V-transposed
// [B*H, DK, S] via LDS-transposed coalesced epilogue.
// ---------------------------------------------------------------------------
template<int ABF, int MODE>
__global__ __launch_bounds__(256, 2)
void gemm_nt(const void* __restrict__ Av, const u16* __restrict__ Wb,
             const float* __restrict__ bias, u16* __restrict__ out)
{
    __shared__ __align__(16) u16 smem[8192 + 4096];   // As 128x64 | Bs 64x64
    u16* As = smem;
    u16* Bs = smem + 8192;
    const int K = 1024;
    int tid  = threadIdx.x;
    int wave = tid >> 6, lane = tid & 63;
    int quad = lane >> 4, l16 = lane & 15;
    int bm = blockIdx.x >> 4;     // 32 M-tiles
    int bn = blockIdx.x & 15;     // 16 N-tiles
    int row0 = bm * 128, col0 = bn * 64;
    int wm = (wave >> 1) * 64, wn = (wave & 1) * 32;

    f32x4 acc[4][2] = {};

    const float* Af = (const float*)Av;
    const u16*   Ab = (const u16*)Av;
    int srow = tid >> 3;          // 0..31
    int scol = (tid & 7) * 8;     // 0..56

    for (int k0 = 0; k0 < K; k0 += 64) {
        uint4 av[4];
        if (!ABF) {
            #pragma unroll
            for (int c = 0; c < 4; ++c) {
                const float* ap = Af + (size_t)(row0 + srow + c * 32) * K + k0 + scol;
                float4 lo = *(const float4*)ap;
                float4 hi = *(const float4*)(ap + 4);
                av[c].x = pack2(lo.x, lo.y); av[c].y = pack2(lo.z, lo.w);
                av[c].z = pack2(hi.x, hi.y); av[c].w = pack2(hi.z, hi.w);
            }
        }
        __syncthreads();
        if (ABF) {
            #pragma unroll
            for (int c = 0; c < 4; ++c) {
                int r0 = (c * 4 + wave) * 8;
                gl2lds16(Ab + (size_t)(row0 + r0 + (lane >> 3)) * K + k0 + (lane & 7) * 8,
                         As + r0 * 64);
            }
        } else {
            #pragma unroll
            for (int c = 0; c < 4; ++c)
                *(uint4*)&As[(srow + c * 32) * 64 + scol] = av[c];
        }
        #pragma unroll
        for (int c = 0; c < 2; ++c) {
            int r0 = (c * 4 + wave) * 8;
            gl2lds16(Wb + (size_t)(col0 + r0 + (lane >> 3)) * K + k0 + (lane & 7) * 8,
                     Bs + r0 * 64);
        }
        __syncthreads();
        #pragma unroll
        for (int kk = 0; kk < 2; ++kk) {
            bf16x8 af[4], bfv[2];
            #pragma unroll
            for (int i = 0; i < 4; ++i)
                af[i] = *(const bf16x8*)&As[(wm + i * 16 + l16) * 64 + kk * 32 + quad * 8];
            #pragma unroll
            for (int j = 0; j < 2; ++j)
                bfv[j] = *(const bf16x8*)&Bs[(wn + j * 16 + l16) * 64 + kk * 32 + quad * 8];
            #pragma unroll
            for (int i = 0; i < 4; ++i)
                #pragma unroll
                for (int j = 0; j < 2; ++j)
                    acc[i][j] = __builtin_amdgcn_mfma_f32_16x16x32_bf16(af[i], bfv[j], acc[i][j], 0, 0, 0);
        }
    }

    if (MODE == 2) {
        // stage C^T into LDS [dk][s] (stride 136), then coalesced store to
        // vt[bh][dk][s].
        __syncthreads();
        u16* Ct = smem;
        #pragma unroll
        for (int j = 0; j < 2; ++j) {
            int dk = wn + j * 16 + l16;
            float bvv = bias[col0 + dk];
            #pragma unroll
            for (int i = 0; i < 4; ++i)
                #pragma unroll
                for (int r = 0; r < 4; ++r)
                    Ct[dk * 136 + wm + i * 16 + quad * 4 + r] = f2bf(acc[i][j][r] + bvv);
        }
        __syncthreads();
        int dk = tid >> 2, seg = (tid & 3) * 32;
        int b = row0 >> 11, h = bn >> 0;   // N-tile 64 == one head
        int bh = b * HH + (h & 15);
        int s0 = row0 & (SS - 1);
        u16* dst = out + ((size_t)bh * DKK + dk) * SS + s0 + seg;
        #pragma unroll
        for (int u = 0; u < 4; ++u)
            *(uint4*)(dst + u * 8) = *(const uint4*)&Ct[dk * 136 + seg + u * 8];
        return;
    }

    #pragma unroll
    for (int j = 0; j < 2; ++j) {
        int n = col0 + wn + j * 16 + l16;
        float bvv = bias[n];
        #pragma unroll
        for (int i = 0; i < 4; ++i) {
            int rbase = row0 + wm + i * 16 + quad * 4;
            #pragma unroll
            for (int r = 0; r < 4; ++r) {
                int m = rbase + r;
                float v = acc[i][j][r] + bvv;
                if (MODE == 0) {
                    int b = m >> 11, s = m & (SS - 1);
                    int h = n >> 6, dk = n & 63;
                    out[(((size_t)(b * HH + h)) * SS + s) * DKK + dk] = f2bf(v);
                } else {
                    out[(size_t)m * DD + n] = f2bf(v);
                }
            }
        }
    }
}

// ---------------------------------------------------------------------------
// Barrier-free flash attention. One wave owns 32 q rows (2 row-tiles of 16).
// K read from global (natural layout) as B-frags; V from global transposed
// vt[bh][dk][s] as B-frags; P round-trips per-wave LDS (stride-72 + quad-XOR
// swizzle: conflict-free). Heavy q-tiles dispatched first; bh pinned per XCD.
// ---------------------------------------------------------------------------
__global__ __launch_bounds__(256, 2)
void attn2(const u16* __restrict__ Qh, const u16* __restrict__ Kh,
           const u16* __restrict__ Vt, const float* __restrict__ comp,
           const float* __restrict__ cpen_p, u16* __restrict__ ctx)
{
    __shared__ __align__(16) u16 Pl[4][2][16 * 72];

    int tid  = threadIdx.x;
    int wave = tid >> 6, lane = tid & 63;
    int quad = lane >> 4, l16 = lane & 15;
    int t = blockIdx.x * 4 + wave;          // 0..2047
    int bh  = t & 31;
    int sub = 63 - (t >> 5);                // heavy (large q0) first
    int q0  = sub * 32;
    int b = bh >> 4, h = bh & 15;
    float cpen = cpen_p[0];

    const u16* Qb = Qh + (size_t)bh * SS * DKK;
    const u16* Kb = Kh + (size_t)bh * SS * DKK;
    const u16* Vb = Vt + (size_t)bh * DKK * SS;   // [dk][s]

    bf16x8 qf[2][2];
    #pragma unroll
    for (int i = 0; i < 2; ++i) {
        int row = q0 + i * 16 + l16;
        qf[i][0] = *(const bf16x8*)&Qb[(size_t)row * DKK + quad * 8];
        qf[i][1] = *(const bf16x8*)&Qb[(size_t)row * DKK + 32 + quad * 8];
    }

    f32x4 o[2][4] = {};
    float mrow[2][4], lrow[2][4];
    #pragma unroll
    for (int i = 0; i < 2; ++i)
        #pragma unroll
        for (int r = 0; r < 4; ++r) { mrow[i][r] = NEG_BIG; lrow[i][r] = 0.f; }

    int ktmax = (q0 + 31) >> 6;

    for (int kt = 0; kt <= ktmax; ++kt) {
        bf16x8 kf[4][2], vf[4][2];
        float pen[4];
        #pragma unroll
        for (int jj = 0; jj < 4; ++jj) {
            const u16* kp = Kb + (size_t)(kt * 64 + jj * 16 + l16) * DKK + quad * 8;
            kf[jj][0] = *(const bf16x8*)kp;
            kf[jj][1] = *(const bf16x8*)(kp + 32);
            const u16* vp = Vb + (size_t)(jj * 16 + l16) * SS + kt * 64 + quad * 8;
            vf[jj][0] = *(const bf16x8*)vp;
            vf[jj][1] = *(const bf16x8*)(vp + 32);
            pen[jj] = cpen * comp[b * SS + kt * 64 + jj * 16 + l16];
        }
        bool diag = (kt == ktmax);

        #pragma unroll
        for (int i = 0; i < 2; ++i) {
            f32x4 sc[4] = {};
            #pragma unroll
            for (int jj = 0; jj < 4; ++jj) {
                sc[jj] = __builtin_amdgcn_mfma_f32_16x16x32_bf16(qf[i][0], kf[jj][0], sc[jj], 0, 0, 0);
                sc[jj] = __builtin_amdgcn_mfma_f32_16x16x32_bf16(qf[i][1], kf[jj][1], sc[jj], 0, 0, 0);
            }
            int myq = q0 + i * 16 + quad * 4;
            #pragma unroll
            for (int jj = 0; jj < 4; ++jj) {
                int kcol = kt * 64 + jj * 16 + l16;
                #pragma unroll
                for (int r = 0; r < 4; ++r) {
                    float sv = sc[jj][r] * 0.125f - pen[jj];
                    if (diag && (kcol > myq + r)) sv = NEG_BIG;
                    sc[jj][r] = sv;
                }
            }
            // online softmax over the row (16 lanes of this quad group)
            float mnew[4], alpha[4];
            #pragma unroll
            for (int r = 0; r < 4; ++r) {
                float mx = fmaxf(fmaxf(sc[0][r], sc[1][r]), fmaxf(sc[2][r], sc[3][r]));
                #pragma unroll
                for (int off = 1; off < 16; off <<= 1)
                    mx = fmaxf(mx, __shfl_xor(mx, off, 64));
                mnew[r] = fmaxf(mrow[i][r], mx);
                alpha[r] = __expf(mrow[i][r] - mnew[r]);
                mrow[i][r] = mnew[r];
            }
            float lsum[4] = {0.f, 0.f, 0.f, 0.f};
            #pragma unroll
            for (int jj = 0; jj < 4; ++jj)
                #pragma unroll
                for (int r = 0; r < 4; ++r) {
                    float p = __expf(sc[jj][r] - mnew[r]);
                    sc[jj][r] = p;
                    lsum[r] += p;
                }
            #pragma unroll
            for (int r = 0; r < 4; ++r) {
                float ts = lsum[r];
                #pragma unroll
                for (int off = 1; off < 16; off <<= 1)
                    ts += __shfl_xor(ts, off, 64);
                lrow[i][r] = lrow[i][r] * alpha[r] + ts;
            }
            #pragma unroll
            for (int jj = 0; jj < 4; ++jj)
                #pragma unroll
                for (int r = 0; r < 4; ++r)
                    o[i][jj][r] *= alpha[r];

            // P: C-layout -> per-wave LDS (swizzled) -> A-layout
            u16* P = Pl[wave][i];
            #pragma unroll
            for (int jj = 0; jj < 4; ++jj) {
                int blk = (jj * 2 + (l16 >> 3)) ^ quad;
                #pragma unroll
                for (int r = 0; r < 4; ++r)
                    P[(quad * 4 + r) * 72 + blk * 8 + (l16 & 7)] = f2bf(sc[jj][r]);
            }
            #pragma unroll
            for (int kk = 0; kk < 2; ++kk) {
                int blk = (kk * 4 + quad) ^ (l16 >> 2);
                bf16x8 pf = *(const bf16x8*)&P[l16 * 72 + blk * 8];
                #pragma unroll
                for (int jj = 0; jj < 4; ++jj)
                    o[i][jj] = __builtin_amdgcn_mfma_f32_16x16x32_bf16(pf, vf[jj][kk], o[i][jj], 0, 0, 0);
            }
        }
    }

    #pragma unroll
    for (int i = 0; i < 2; ++i) {
        float inv[4];
        #pragma unroll
        for (int r = 0; r < 4; ++r) inv[r] = 1.f / lrow[i][r];
        #pragma unroll
        for (int jj = 0; jj < 4; ++jj) {
            int d = jj * 16 + l16;
            #pragma unroll
            for (int r = 0; r < 4; ++r) {
                int q = q0 + i * 16 + quad * 4 + r;
                ctx[((size_t)(b * SS + q)) * DD + h * DKK + d] = f2bf(o[i][jj][r] * inv[r]);
            }
        }
    }
}

// ---------------------------------------------------------------------------
// Residual + LayerNorm: out = LN(po + query) * g + b.  po bf16; rest f32.
// ---------------------------------------------------------------------------
__global__ __launch_bounds__(256)
void ln_res(const u16* __restrict__ po, const float* __restrict__ query,
            const float* __restrict__ g, const float* __restrict__ bb,
            float* __restrict__ out)
{
    int row = blockIdx.x;
    int tid = threadIdx.x;
    int lane = tid & 63, wave = tid >> 6;
    size_t base = (size_t)row * DD + tid * 4;
    __align__(8) u16 tp[4];
    *(uint2*)tp = *(const uint2*)(po + base);
    float4 q4 = *(const float4*)(query + base);
    float x[4];
    x[0] = bf2f(tp[0]) + q4.x; x[1] = bf2f(tp[1]) + q4.y;
    x[2] = bf2f(tp[2]) + q4.z; x[3] = bf2f(tp[3]) + q4.w;
    float s1 = 0.f, s2 = 0.f;
    #pragma unroll
    for (int i = 0; i < 4; ++i) { s1 += x[i]; s2 += x[i] * x[i]; }
    #pragma unroll
    for (int off = 1; off < 64; off <<= 1) {
        s1 += __shfl_xor(s1, off, 64);
        s2 += __shfl_xor(s2, off, 64);
    }
    __shared__ float red1[4], red2[4];
    if (lane == 0) { red1[wave] = s1; red2[wave] = s2; }
    __syncthreads();
    float t1 = red1[0] + red1[1] + red1[2] + red1[3];
    float t2 = red2[0] + red2[1] + red2[2] + red2[3];
    float mean = t1 * (1.f / 1024.f);
    float var  = fmaxf(t2 * (1.f / 1024.f) - mean * mean, 0.f);
    float rstd = rsqrtf(var + 1e-5f);
    float4 g4 = *(const float4*)(g + tid * 4);
    float4 b4 = *(const float4*)(bb + tid * 4);
    float4 ov;
    ov.x = (x[0] - mean) * rstd * g4.x + b4.x;
    ov.y = (x[1] - mean) * rstd * g4.y + b4.y;
    ov.z = (x[2] - mean) * rstd * g4.z + b4.z;
    ov.w = (x[3] - mean) * rstd * g4.w + b4.w;
    *(float4*)(out + base) = ov;
}

extern "C" void kernel_launch(void* const* d_in, const int* in_sizes, int n_in,
                              void* d_out, int out_size, void* d_ws, size_t ws_size,
                              hipStream_t stream)
{
    const float* query = (const float*)d_in[0];
    const float* key   = (const float*)d_in[1];
    const float* value = (const float*)d_in[2];
    const float* comp  = (const float*)d_in[3];
    // d_in[4] = mask (causal tril) — computed analytically, ignored
    const float* wq = (const float*)d_in[5];
    const float* bq = (const float*)d_in[6];
    const float* wk = (const float*)d_in[7];
    const float* bk = (const float*)d_in[8];
    const float* wv = (const float*)d_in[9];
    const float* bv = (const float*)d_in[10];
    const float* wo = (const float*)d_in[11];
    const float* bo = (const float*)d_in[12];
    const float* lng = (const float*)d_in[13];
    const float* lnb = (const float*)d_in[14];
    const float* cpen = (const float*)d_in[15];
    float* outp = (float*)d_out;

    const size_t NE = (size_t)MROWS * DD;    // 4 Mi elements
    const size_t WE = (size_t)DD * DD;       // 1 Mi elements
    // ws (24 MB): qh | kh (-> po) | vt
    u16* qh = (u16*)d_ws;
    u16* kh = qh + NE;
    u16* vt = kh + NE;
    u16* po = kh;
    // d_out (16 MB): [0,8M) bf16 weights wq|wk|wv|wo, [8M,16M) ctx bf16.
    // Both dead before ln_res rewrites d_out.
    u16* wbf = (u16*)d_out;
    u16* cx  = wbf + 4 * WE;

    cvt_w<<<dim3(1024, 4), 256, 0, stream>>>(wq, wk, wv, wo, wbf);
    gemm_nt<0, 0><<<512, 256, 0, stream>>>((const void*)query, wbf + 0 * WE, bq, qh);
    gemm_nt<0, 0><<<512, 256, 0, stream>>>((const void*)key,   wbf + 1 * WE, bk, kh);
    gemm_nt<0, 2><<<512, 256, 0, stream>>>((const void*)value, wbf + 2 * WE, bv, vt);
    attn2<<<512, 256, 0, stream>>>(qh, kh, vt, comp, cpen, cx);
    gemm_nt<1, 1><<<512, 256, 0, stream>>>((const void*)cx, wbf + 3 * WE, bo, po);
    ln_res<<<MROWS, 256, 0, stream>>>(po, query, lng, lnb, outp);
}

// Round 5
// 325.431 us; speedup vs baseline: 1.7520x; 1.3865x over previous
//
#include <hip/hip_runtime.h>

#define BB 2
#define SS 2048
#define DD 1024
#define HH 16
#define DKK 64
#define MROWS (BB*SS)
#define NEG_BIG (-30000.0f)

typedef unsigned short u16;
typedef unsigned int u32;
typedef __bf16 bf16x8 __attribute__((ext_vector_type(8)));
typedef float f32x4 __attribute__((ext_vector_type(4)));

__device__ __forceinline__ u16 f2bf(float f) {
    union { float f; u32 i; } w; w.f = f;
    u32 u = w.i;
    return (u16)((u + 0x7fffu + ((u >> 16) & 1u)) >> 16);
}
__device__ __forceinline__ float bf2f(u16 u) {
    union { u32 i; float f; } w; w.i = ((u32)u) << 16; return w.f;
}
__device__ __forceinline__ u32 pack2(float lo, float hi) {
    union { float f; u32 i; } a, b; a.f = lo; b.f = hi;
    return (a.i >> 16) | (b.i & 0xffff0000u);
}
__device__ __forceinline__ void gl2lds16(const u16* g, u16* l) {
    __builtin_amdgcn_global_load_lds(
        (const __attribute__((address_space(1))) void*)g,
        (__attribute__((address_space(3))) void*)l, 16, 0, 0);
}

// ---------------------------------------------------------------------------
// f32 -> bf16 converters.
// ---------------------------------------------------------------------------
__global__ __launch_bounds__(256)
void cvt_w(const float* __restrict__ w0, const float* __restrict__ w1,
           const float* __restrict__ w2, const float* __restrict__ w3,
           u16* __restrict__ dst)
{
    const float* srcs[4] = {w0, w1, w2, w3};
    const float* s = srcs[blockIdx.y];
    int i = (blockIdx.x * 256 + threadIdx.x) * 8;
    float4 a = *(const float4*)(s + i);
    float4 b = *(const float4*)(s + i + 4);
    uint4 o;
    o.x = pack2(a.x, a.y); o.y = pack2(a.z, a.w);
    o.z = pack2(b.x, b.y); o.w = pack2(b.z, b.w);
    *(uint4*)(dst + (size_t)blockIdx.y * DD * DD + i) = o;
}

__global__ __launch_bounds__(256)
void cvt_x(const float* __restrict__ s, u16* __restrict__ dst)
{
    int i = (blockIdx.x * 256 + threadIdx.x) * 8;
    float4 a = *(const float4*)(s + i);
    float4 b = *(const float4*)(s + i + 4);
    uint4 o;
    o.x = pack2(a.x, a.y); o.y = pack2(a.z, a.w);
    o.z = pack2(b.x, b.y); o.w = pack2(b.z, b.w);
    *(uint4*)(dst + i) = o;
}

// ---------------------------------------------------------------------------
// NT GEMM (all-bf16): out[m,n] = sum_k A[m,k]*W[n,k] + bias[n].
// M=4096, N=1024, K=1024. Tile 128(M) x 64(N), BK=64, 4 waves (2x2),
// wave tile 64x32. Grid 512 = 2 blocks/CU. Staging via global_load_lds x16.
// MODE 0: head layout [B*H,S,DK]; MODE 1: plain [m,n];
// MODE 2: V-transposed [B*H, DK, S] via LDS-transposed coalesced epilogue.
// ---------------------------------------------------------------------------
template<int MODE>
__global__ __launch_bounds__(256, 2)
void gemm_nt(const u16* __restrict__ A, const u16* __restrict__ Wb,
             const float* __restrict__ bias, u16* __restrict__ out)
{
    __shared__ __align__(16) u16 smem[8192 + 4096];   // As 128x64 | Bs 64x64
    u16* As = smem;
    u16* Bs = smem + 8192;
    const int K = 1024;
    int tid  = threadIdx.x;
    int wave = tid >> 6, lane = tid & 63;
    int quad = lane >> 4, l16 = lane & 15;
    int bm = blockIdx.x >> 4;     // 32 M-tiles
    int bn = blockIdx.x & 15;     // 16 N-tiles
    int row0 = bm * 128, col0 = bn * 64;
    int wm = (wave >> 1) * 64, wn = (wave & 1) * 32;

    f32x4 acc[4][2] = {};

    for (int k0 = 0; k0 < K; k0 += 64) {
        __syncthreads();
        #pragma unroll
        for (int c = 0; c < 4; ++c) {
            int r0 = (c * 4 + wave) * 8;
            gl2lds16(A + (size_t)(row0 + r0 + (lane >> 3)) * K + k0 + (lane & 7) * 8,
                     As + r0 * 64);
        }
        #pragma unroll
        for (int c = 0; c < 2; ++c) {
            int r0 = (c * 4 + wave) * 8;
            gl2lds16(Wb + (size_t)(col0 + r0 + (lane >> 3)) * K + k0 + (lane & 7) * 8,
                     Bs + r0 * 64);
        }
        __syncthreads();
        #pragma unroll
        for (int kk = 0; kk < 2; ++kk) {
            bf16x8 af[4], bfv[2];
            #pragma unroll
            for (int i = 0; i < 4; ++i)
                af[i] = *(const bf16x8*)&As[(wm + i * 16 + l16) * 64 + kk * 32 + quad * 8];
            #pragma unroll
            for (int j = 0; j < 2; ++j)
                bfv[j] = *(const bf16x8*)&Bs[(wn + j * 16 + l16) * 64 + kk * 32 + quad * 8];
            #pragma unroll
            for (int i = 0; i < 4; ++i)
                #pragma unroll
                for (int j = 0; j < 2; ++j)
                    acc[i][j] = __builtin_amdgcn_mfma_f32_16x16x32_bf16(af[i], bfv[j], acc[i][j], 0, 0, 0);
        }
    }

    if (MODE == 2) {
        __syncthreads();
        u16* Ct = smem;   // [dk][s] stride 136
        #pragma unroll
        for (int j = 0; j < 2; ++j) {
            int dk = wn + j * 16 + l16;
            float bvv = bias[col0 + dk];
            #pragma unroll
            for (int i = 0; i < 4; ++i)
                #pragma unroll
                for (int r = 0; r < 4; ++r)
                    Ct[dk * 136 + wm + i * 16 + quad * 4 + r] = f2bf(acc[i][j][r] + bvv);
        }
        __syncthreads();
        int dk = tid >> 2, seg = (tid & 3) * 32;
        int b = row0 >> 11;
        int bh = b * HH + bn;
        int s0 = row0 & (SS - 1);
        u16* dst = out + ((size_t)bh * DKK + dk) * SS + s0 + seg;
        #pragma unroll
        for (int u = 0; u < 4; ++u)
            *(uint4*)(dst + u * 8) = *(const uint4*)&Ct[dk * 136 + seg + u * 8];
        return;
    }

    #pragma unroll
    for (int j = 0; j < 2; ++j) {
        int n = col0 + wn + j * 16 + l16;
        float bvv = bias[n];
        #pragma unroll
        for (int i = 0; i < 4; ++i) {
            int rbase = row0 + wm + i * 16 + quad * 4;
            #pragma unroll
            for (int r = 0; r < 4; ++r) {
                int m = rbase + r;
                float v = acc[i][j][r] + bvv;
                if (MODE == 0) {
                    int b = m >> 11, s = m & (SS - 1);
                    int h = n >> 6, dk = n & 63;
                    out[(((size_t)(b * HH + h)) * SS + s) * DKK + dk] = f2bf(v);
                } else {
                    out[(size_t)m * DD + n] = f2bf(v);
                }
            }
        }
    }
}

// ---------------------------------------------------------------------------
// Flash attention, transposed scores. One wave per 32 q-rows; single-wave
// blocks (64 thr), grid 2048 heavy-first -> scheduler backfills (load
// balance). S^T = K Q^T so the softmax row (over k) is in-lane + cross-quad
// (2 shuffles). P^T -> LDS[q][k] via ds_write_b64; PV as O^T = V^T P.
// ---------------------------------------------------------------------------
__global__ __launch_bounds__(64, 2)
void attn3(const u16* __restrict__ Qh, const u16* __restrict__ Kh,
           const u16* __restrict__ Vt, const float* __restrict__ comp,
           const float* __restrict__ cpen_p, u16* __restrict__ ctx)
{
    __shared__ __align__(16) u16 Pb[16 * 72];

    int lane = threadIdx.x;
    int quad = lane >> 4, l16 = lane & 15;
    int t = blockIdx.x;
    int bh  = t & 31;
    int sub = 63 - (t >> 5);       // heavy q-tiles dispatched first
    int q0  = sub * 32;
    int b = bh >> 4, h = bh & 15;
    float cpen = cpen_p[0];

    const u16* Qb = Qh + (size_t)bh * SS * DKK;
    const u16* Kb = Kh + (size_t)bh * SS * DKK;
    const u16* Vb = Vt + (size_t)bh * DKK * SS;   // [dk][s]

    bf16x8 qf[2][2];
    #pragma unroll
    for (int i = 0; i < 2; ++i) {
        int row = q0 + i * 16 + l16;
        qf[i][0] = *(const bf16x8*)&Qb[(size_t)row * DKK + quad * 8];
        qf[i][1] = *(const bf16x8*)&Qb[(size_t)row * DKK + 32 + quad * 8];
    }

    f32x4 o[2][4] = {};
    float m_i[2] = {NEG_BIG, NEG_BIG};
    float l_i[2] = {0.f, 0.f};

    int ktmax = (q0 + 31) >> 6;

    for (int kt = 0; kt <= ktmax; ++kt) {
        // K fragments (A-operand: m = key row)
        bf16x8 kf[4][2], vf[4][2];
        f32x4 c4[4];
        const u16* kbase = Kb + (size_t)(kt * 64 + l16) * DKK + quad * 8;
        const u16* vbase = Vb + (size_t)l16 * SS + kt * 64 + quad * 8;
        #pragma unroll
        for (int jj = 0; jj < 4; ++jj) {
            kf[jj][0] = *(const bf16x8*)(kbase + (size_t)jj * 16 * DKK);
            kf[jj][1] = *(const bf16x8*)(kbase + (size_t)jj * 16 * DKK + 32);
            vf[jj][0] = *(const bf16x8*)(vbase + (size_t)jj * 16 * SS);
            vf[jj][1] = *(const bf16x8*)(vbase + (size_t)jj * 16 * SS + 32);
            c4[jj] = *(const f32x4*)&comp[b * SS + kt * 64 + jj * 16 + quad * 4];
        }
        bool diag = (kt == ktmax);

        #pragma unroll
        for (int i = 0; i < 2; ++i) {
            // S^T tile: D[m=k][n=q]
            f32x4 sc[4] = {};
            #pragma unroll
            for (int jj = 0; jj < 4; ++jj) {
                sc[jj] = __builtin_amdgcn_mfma_f32_16x16x32_bf16(kf[jj][0], qf[i][0], sc[jj], 0, 0, 0);
                sc[jj] = __builtin_amdgcn_mfma_f32_16x16x32_bf16(kf[jj][1], qf[i][1], sc[jj], 0, 0, 0);
            }
            int myq = q0 + i * 16 + l16;
            #pragma unroll
            for (int jj = 0; jj < 4; ++jj) {
                int kb0 = kt * 64 + jj * 16 + quad * 4;
                #pragma unroll
                for (int r = 0; r < 4; ++r) {
                    float sv = sc[jj][r] * 0.125f - cpen * c4[jj][r];
                    if (diag && (kb0 + r > myq)) sv = NEG_BIG;
                    sc[jj][r] = sv;
                }
            }
            // softmax row = fixed q (this lane) over in-lane k + cross-quad
            float mx = NEG_BIG;
            #pragma unroll
            for (int jj = 0; jj < 4; ++jj)
                #pragma unroll
                for (int r = 0; r < 4; ++r) mx = fmaxf(mx, sc[jj][r]);
            mx = fmaxf(mx, __shfl_xor(mx, 16, 64));
            mx = fmaxf(mx, __shfl_xor(mx, 32, 64));
            float mnew = fmaxf(m_i[i], mx);
            float alpha = __expf(m_i[i] - mnew);
            m_i[i] = mnew;
            float ls = 0.f;
            #pragma unroll
            for (int jj = 0; jj < 4; ++jj)
                #pragma unroll
                for (int r = 0; r < 4; ++r) {
                    float p = __expf(sc[jj][r] - mnew);
                    sc[jj][r] = p;
                    ls += p;
                }
            ls += __shfl_xor(ls, 16, 64);
            ls += __shfl_xor(ls, 32, 64);
            l_i[i] = l_i[i] * alpha + ls;
            #pragma unroll
            for (int jj = 0; jj < 4; ++jj)
                #pragma unroll
                for (int r = 0; r < 4; ++r) o[i][jj][r] *= alpha;

            // P^T -> LDS [q=l16][k] (stride 72), b64 writes; same-wave in-order
            #pragma unroll
            for (int jj = 0; jj < 4; ++jj) {
                uint2 pw;
                pw.x = pack2(sc[jj][0], sc[jj][1]);
                pw.y = pack2(sc[jj][2], sc[jj][3]);
                *(uint2*)&Pb[l16 * 72 + jj * 16 + quad * 4] = pw;
            }
            // O^T += V^T P : A=vf (m=d), B=P[q][k]
            #pragma unroll
            for (int kk = 0; kk < 2; ++kk) {
                bf16x8 pf = *(const bf16x8*)&Pb[l16 * 72 + kk * 32 + quad * 8];
                #pragma unroll
                for (int jj = 0; jj < 4; ++jj)
                    o[i][jj] = __builtin_amdgcn_mfma_f32_16x16x32_bf16(vf[jj][kk], pf, o[i][jj], 0, 0, 0);
            }
        }
    }

    // epilogue: O^T[d][q] -> LDS transpose -> coalesced ctx[q][h*64+d]
    #pragma unroll
    for (int i = 0; i < 2; ++i) {
        float inv = 1.f / l_i[i];
        #pragma unroll
        for (int jj = 0; jj < 4; ++jj) {
            uint2 ow;
            ow.x = pack2(o[i][jj][0] * inv, o[i][jj][1] * inv);
            ow.y = pack2(o[i][jj][2] * inv, o[i][jj][3] * inv);
            *(uint2*)&Pb[l16 * 72 + jj * 16 + quad * 4] = ow;
        }
        int qq = lane >> 2;
        int dseg = (lane & 3) * 16;
        uint4 r0 = *(const uint4*)&Pb[qq * 72 + dseg];
        uint4 r1 = *(const uint4*)&Pb[qq * 72 + dseg + 8];
        u16* dst = ctx + ((size_t)(b * SS + q0 + i * 16 + qq)) * DD + h * DKK + dseg;
        *(uint4*)dst = r0;
        *(uint4*)(dst + 8) = r1;
    }
}

// ---------------------------------------------------------------------------
// Residual + LayerNorm: out = LN(po + query) * g + b.  po bf16; rest f32.
// ---------------------------------------------------------------------------
__global__ __launch_bounds__(256)
void ln_res(const u16* __restrict__ po, const float* __restrict__ query,
            const float* __restrict__ g, const float* __restrict__ bb,
            float* __restrict__ out)
{
    int row = blockIdx.x;
    int tid = threadIdx.x;
    int lane = tid & 63, wave = tid >> 6;
    size_t base = (size_t)row * DD + tid * 4;
    __align__(8) u16 tp[4];
    *(uint2*)tp = *(const uint2*)(po + base);
    float4 q4 = *(const float4*)(query + base);
    float x[4];
    x[0] = bf2f(tp[0]) + q4.x; x[1] = bf2f(tp[1]) + q4.y;
    x[2] = bf2f(tp[2]) + q4.z; x[3] = bf2f(tp[3]) + q4.w;
    float s1 = 0.f, s2 = 0.f;
    #pragma unroll
    for (int i = 0; i < 4; ++i) { s1 += x[i]; s2 += x[i] * x[i]; }
    #pragma unroll
    for (int off = 1; off < 64; off <<= 1) {
        s1 += __shfl_xor(s1, off, 64);
        s2 += __shfl_xor(s2, off, 64);
    }
    __shared__ float red1[4], red2[4];
    if (lane == 0) { red1[wave] = s1; red2[wave] = s2; }
    __syncthreads();
    float t1 = red1[0] + red1[1] + red1[2] + red1[3];
    float t2 = red2[0] + red2[1] + red2[2] + red2[3];
    float mean = t1 * (1.f / 1024.f);
    float var  = fmaxf(t2 * (1.f / 1024.f) - mean * mean, 0.f);
    float rstd = rsqrtf(var + 1e-5f);
    float4 g4 = *(const float4*)(g + tid * 4);
    float4 b4 = *(const float4*)(bb + tid * 4);
    float4 ov;
    ov.x = (x[0] - mean) * rstd * g4.x + b4.x;
    ov.y = (x[1] - mean) * rstd * g4.y + b4.y;
    ov.z = (x[2] - mean) * rstd * g4.z + b4.z;
    ov.w = (x[3] - mean) * rstd * g4.w + b4.w;
    *(float4*)(out + base) = ov;
}

extern "C" void kernel_launch(void* const* d_in, const int* in_sizes, int n_in,
                              void* d_out, int out_size, void* d_ws, size_t ws_size,
                              hipStream_t stream)
{
    const float* query = (const float*)d_in[0];
    const float* key   = (const float*)d_in[1];
    const float* value = (const float*)d_in[2];
    const float* comp  = (const float*)d_in[3];
    // d_in[4] = mask (causal tril) — computed analytically, ignored
    const float* wq = (const float*)d_in[5];
    const float* bq = (const float*)d_in[6];
    const float* wk = (const float*)d_in[7];
    const float* bk = (const float*)d_in[8];
    const float* wv = (const float*)d_in[9];
    const float* bv = (const float*)d_in[10];
    const float* wo = (const float*)d_in[11];
    const float* bo = (const float*)d_in[12];
    const float* lng = (const float*)d_in[13];
    const float* lnb = (const float*)d_in[14];
    const float* cpen = (const float*)d_in[15];
    float* outp = (float*)d_out;

    const size_t NE = (size_t)MROWS * DD;    // 4 Mi elements
    const size_t WE = (size_t)DD * DD;       // 1 Mi elements
    // ws (24 MB bf16): qh | kh (-> po) | vt
    u16* qh = (u16*)d_ws;
    u16* kh = qh + NE;
    u16* vt = kh + NE;
    u16* po = kh;
    // d_out (16 MB): [0,8M) bf16 weights wq|wk|wv|wo; [8M,16M) staging region
    // (activation bf16 / ctx). All dead before ln_res rewrites d_out.
    u16* wbf = (u16*)d_out;
    u16* cxr = wbf + 4 * WE;

    cvt_w<<<dim3(512, 4), 256, 0, stream>>>(wq, wk, wv, wo, wbf);
    cvt_x<<<2048, 256, 0, stream>>>(query, cxr);
    gemm_nt<0><<<512, 256, 0, stream>>>(cxr, wbf + 0 * WE, bq, qh);
    cvt_x<<<2048, 256, 0, stream>>>(key, cxr);
    gemm_nt<0><<<512, 256, 0, stream>>>(cxr, wbf + 1 * WE, bk, kh);
    cvt_x<<<2048, 256, 0, stream>>>(value, cxr);
    gemm_nt<2><<<512, 256, 0, stream>>>(cxr, wbf + 2 * WE, bv, vt);
    attn3<<<2048, 64, 0, stream>>>(qh, kh, vt, comp, cpen, cxr);
    gemm_nt<1><<<512, 256, 0, stream>>>(cxr, wbf + 3 * WE, bo, po);
    ln_res<<<MROWS, 256, 0, stream>>>(po, query, lng, lnb, outp);
}